// Round 1
// baseline (244.687 us; speedup 1.0000x reference)
//
#include <hip/hip_runtime.h>

// CloudRasterizerOversample: trilinear splat of M points into a
// (NV_HI=256, 512, 512) cube followed by 4x4x4 mean-pooling to (64,128,128).
// Key identity: pooling is linear, so splat directly into the LOW-RES cube
// (4 MB, fits in L2/L3) with weight flux*w/64. Corners sharing a low-res cell
// are merged, cutting atomics from 8/point to ~1.95/point on average.

#define N_PIX_LO 128
#define NV_LO 64

__global__ __launch_bounds__(256) void cloud_raster_lo_kernel(
    const float* __restrict__ ra,
    const float* __restrict__ dec,
    const float* __restrict__ vel,
    const float* __restrict__ flux,
    float* __restrict__ out,
    int M)
{
    int i = blockIdx.x * blockDim.x + threadIdx.x;
    if (i >= M) return;

    // Exact reference arithmetic (fp32, IEEE divide — must match np binning):
    // FOV_HALF_HI = 6.3875, PIX_HI = 0.025, VEL0_HI = -404.6875, DV_HI = 3.125
    float gx = (ra[i]  + 6.3875f)   / 0.025f;
    float gy = (dec[i] + 6.3875f)   / 0.025f;
    float gv = (vel[i] + 404.6875f) / 3.125f;

    float fxf = floorf(gx);
    float fyf = floorf(gy);
    float fvf = floorf(gv);
    int ix0 = (int)fxf;
    int iy0 = (int)fyf;
    int iv0 = (int)fvf;
    float fx = gx - fxf;
    float fy = gy - fyf;
    float fv = gv - fvf;

    // valid: ix0 in [0, 510], iy0 in [0, 510], iv0 in [0, 254]
    if (ix0 < 0 || ix0 >= 511 || iy0 < 0 || iy0 >= 511 || iv0 < 0 || iv0 >= 255) return;

    float f = flux[i] * 0.015625f;   // flux / 64 (mean-pool folded in)

    // Per-axis: low-res cell and merged weights. Corners i0,i0+1 share a
    // low-res cell unless (i0 & 3) == 3.
    int cx = ix0 >> 2;  bool bx = (ix0 & 3) == 3;
    int cy = iy0 >> 2;  bool by = (iy0 & 3) == 3;
    int cv = iv0 >> 2;  bool bv = (iv0 & 3) == 3;

    float wx0 = bx ? (1.0f - fx) : 1.0f;  float wx1 = fx;   int nx = bx ? 2 : 1;
    float wy0 = by ? (1.0f - fy) : 1.0f;  float wy1 = fy;   int ny = by ? 2 : 1;
    float wv0 = bv ? (1.0f - fv) : 1.0f;  float wv1 = fv;   int nv = bv ? 2 : 1;

    #pragma unroll 2
    for (int a = 0; a < nv; ++a) {
        float wva = a ? wv1 : wv0;
        int   iva = cv + a;
        #pragma unroll 2
        for (int b = 0; b < ny; ++b) {
            float wab = f * wva * (b ? wy1 : wy0);
            int base = ((iva * N_PIX_LO) + (cy + b)) * N_PIX_LO + cx;
            #pragma unroll 2
            for (int c = 0; c < nx; ++c) {
                atomicAdd(&out[base + c], wab * (c ? wx1 : wx0));
            }
        }
    }
}

extern "C" void kernel_launch(void* const* d_in, const int* in_sizes, int n_in,
                              void* d_out, int out_size, void* d_ws, size_t ws_size,
                              hipStream_t stream) {
    const float* ra   = (const float*)d_in[0];
    const float* dec  = (const float*)d_in[1];
    const float* vel  = (const float*)d_in[2];
    const float* flux = (const float*)d_in[3];
    float* out = (float*)d_out;
    int M = in_sizes[0];

    // d_out is re-poisoned to 0xAA before every call — zero it on-stream.
    hipMemsetAsync(out, 0, (size_t)out_size * sizeof(float), stream);

    int block = 256;
    int grid = (M + block - 1) / block;
    cloud_raster_lo_kernel<<<grid, block, 0, stream>>>(ra, dec, vel, flux, out, M);
}